// Round 2
// baseline (180.380 us; speedup 1.0000x reference)
//
#include <hip/hip_runtime.h>

// x [B=128, C=3, L=256, L=256] fp32; X/Y/W/H [N=4, B=128] int32.
// Output: x with pixels inside any of the N boxes zeroed (broadcast over C).
//
// Memory-bound: 96 MiB read + 96 MiB write -> ~32 us floor at 6.3 TB/s.
// Grid is 2D (192 x 128): blockIdx.y == sample index b, so the 16 box-param
// loads are provably wave-uniform -> compiler emits scalar s_load (zero VMEM).
// Each thread handles one float4; each wave covers exactly one image row, so
// the row predicate is wave-uniform. Loads are skipped (exec-masked) when all
// 4 elements are inside a box; store is nontemporal (streaming, no L2 reuse).

constexpr int BB = 128;
constexpr int CC = 3;
constexpr int LL = 256;
constexpr int NN = 4;
constexpr int BLOCKS_PER_B = CC * LL * LL / 4 / 256;   // 192

__global__ __launch_bounds__(256) void mask_square_kernel(
    const float4* __restrict__ x,
    const int* __restrict__ Xb,
    const int* __restrict__ Yb,
    const int* __restrict__ Wb,
    const int* __restrict__ Hb,
    float4* __restrict__ out)
{
    const int b    = blockIdx.y;                                   // uniform
    const int i4   = (b * BLOCKS_PER_B + blockIdx.x) * 256 + threadIdx.x;
    const int col0 = (i4 & 63) << 2;
    const int row  = (i4 >> 6) & (LL - 1);

    int m0 = 0, m1 = 0, m2 = 0, m3 = 0;
#pragma unroll
    for (int n = 0; n < NN; ++n) {
        const int Xn = Xb[n * BB + b];   // scalar loads (b uniform)
        const int Yn = Yb[n * BB + b];
        const int Wn = Wb[n * BB + b];
        const int Hn = Hb[n * BB + b];
        const int rin = (row >= Yn) & (row <= Yn + Hn);            // wave-uniform
        const int lo = Xn, hi = Xn + Wn;
        m0 |= rin & (col0     >= lo) & (col0     <= hi);
        m1 |= rin & (col0 + 1 >= lo) & (col0 + 1 <= hi);
        m2 |= rin & (col0 + 2 >= lo) & (col0 + 2 <= hi);
        m3 |= rin & (col0 + 3 >= lo) & (col0 + 3 <= hi);
    }

    float4 v = make_float4(0.0f, 0.0f, 0.0f, 0.0f);
    if (!(m0 & m1 & m2 & m3)) {          // skip fetch when whole float4 masked
        v = x[i4];
        if (m0) v.x = 0.0f;
        if (m1) v.y = 0.0f;
        if (m2) v.z = 0.0f;
        if (m3) v.w = 0.0f;
    }

    __builtin_nontemporal_store(v.x, &out[i4].x);
    __builtin_nontemporal_store(v.y, &out[i4].y);
    __builtin_nontemporal_store(v.z, &out[i4].z);
    __builtin_nontemporal_store(v.w, &out[i4].w);
}

extern "C" void kernel_launch(void* const* d_in, const int* in_sizes, int n_in,
                              void* d_out, int out_size, void* d_ws, size_t ws_size,
                              hipStream_t stream) {
    const float4* x  = (const float4*)d_in[0];
    const int*    Xb = (const int*)d_in[1];
    const int*    Yb = (const int*)d_in[2];
    const int*    Wb = (const int*)d_in[3];
    const int*    Hb = (const int*)d_in[4];
    float4*       o  = (float4*)d_out;

    dim3 grid(BLOCKS_PER_B, BB);   // 192 x 128 blocks
    mask_square_kernel<<<grid, 256, 0, stream>>>(x, Xb, Yb, Wb, Hb, o);
}